// Round 1
// 8928.159 us; speedup vs baseline: 1.0011x; 1.0011x over previous
//
#include <hip/hip_runtime.h>

#define T_LEN 8192
#define HH 128
#define G4 512
#define E_DIM 50
#define KT 23
#define START_T 21
#define STOP_T 22
#define NEGV -10000.0f

__device__ __forceinline__ float rl(float v, int lane) {
  return __int_as_float(__builtin_amdgcn_readlane(__float_as_int(v), lane));
}

template <int CTRL>
__device__ __forceinline__ float quadbcast(float x) {
  return __int_as_float(
      __builtin_amdgcn_mov_dpp(__float_as_int(x), CTRL, 0xF, 0xF, true));
}

// Packed fp32 FMA (VOP3P, arch-VGPR forced).
__device__ __forceinline__ void pkfma(float2& acc, const float2 w, const float2 h) {
  asm volatile("v_pk_fma_f32 %0, %1, %2, %0" : "+v"(acc) : "v"(w), "v"(h));
}

// LIGHT ballast: ONE dependent-chain FMA wave per CU (~1.6% VALU duty).
// R6 evidence: this exact style boosted k_vit 12x; the heavy 512-thread
// version did NOT boost k_lstm (power-limited DPM theory).
template <int BURST>
__device__ __forceinline__ void ballast_spin(const int* flag, int target, float seed,
                                             float* sink) {
  float x = seed;
  const float aa = 1.0000001f, bb = 1e-7f;
  while (__hip_atomic_load(flag, __ATOMIC_RELAXED, __HIP_MEMORY_SCOPE_AGENT) < target) {
#pragma unroll
    for (int q = 0; q < BURST; ++q) x = fmaf(x, aa, bb);
  }
  if (x == 12345.678f) *sink = x;   // unprovable -> loop not removable
}

// ---------------------------------------------------------------------------
// K1: pre[t][j] = Wih[row(j)] . x_t + bih + bhh   (row permuted: r=((j&3)<<7)|(j>>2))
// ---------------------------------------------------------------------------
__global__ __launch_bounds__(512) void k_pre(
    const int* __restrict__ sentence, const float* __restrict__ embed,
    const float* __restrict__ Wih_f, const float* __restrict__ bih_f, const float* __restrict__ bhh_f,
    const float* __restrict__ Wih_b, const float* __restrict__ bih_b, const float* __restrict__ bhh_b,
    float* __restrict__ pre_f, float* __restrict__ pre_b)
{
  const int dir = blockIdx.x >> 8;
  const int t0 = (blockIdx.x & 255) * 32;
  const float* __restrict__ Wih = dir ? Wih_b : Wih_f;
  const float* __restrict__ bi  = dir ? bih_b : bih_f;
  const float* __restrict__ bh  = dir ? bhh_b : bhh_f;
  float* __restrict__ pre = dir ? pre_b : pre_f;
  const int j = threadIdx.x;
  const int r = ((j & 3) << 7) | (j >> 2);
  float w[E_DIM];
  {
    const float2* w2 = (const float2*)(Wih + r * E_DIM);
#pragma unroll
    for (int q = 0; q < 25; ++q) { float2 v = w2[q]; w[2*q] = v.x; w[2*q+1] = v.y; }
  }
  const float bias = bi[r] + bh[r];
  __shared__ float xs[32][E_DIM];
  __shared__ int sidx[32];
  if (j < 32) sidx[j] = sentence[t0 + j];
  __syncthreads();
  for (int i = j; i < 32 * E_DIM; i += 512) {
    int tl = i / E_DIM;
    int e = i - tl * E_DIM;
    xs[tl][e] = embed[sidx[tl] * E_DIM + e];
  }
  __syncthreads();
  for (int tl = 0; tl < 32; ++tl) {
    float a0 = bias, a1 = 0.f;
#pragma unroll
    for (int e = 0; e < E_DIM; e += 2) {
      a0 += w[e]     * xs[tl][e];
      a1 += w[e + 1] * xs[tl][e + 1];
    }
    pre[(t0 + tl) * G4 + j] = a0 + a1;
  }
}

// ---------------------------------------------------------------------------
// K2: serial LSTM, 1 CU/dir (R5 structure: pk_fma, depth-2 pre prefetch,
// 1 __syncthreads/step, DPP quad broadcasts). Blocks >=2: LIGHT ballast —
// only lanes <64 stay (1 wave/CU dependent-FMA spin), rest exit.
//
// R7 FIX: __launch_bounds__(512, 2) capped the allocator at ~128 VGPRs
// (VGPR_Count=80 measured), so w[64] (128 VGPRs of Whh) could NOT stay
// register-resident -> compiler sank a large fraction of the loop-invariant
// Whh loads INTO the 8192-step loop (L2 re-reads ~100-250 KB/step/CU at
// ~135 GB/s/CU == the observed 950 ns/step). (512, 1) gives the 256-VGPR
// launchability bound for an 8-wave block; ~190 VGPRs needed -> resident.
// ---------------------------------------------------------------------------
__global__ __launch_bounds__(512, 1) void k_lstm(
    const float* __restrict__ Whh_f, const float* __restrict__ Whh_b,
    const float* __restrict__ h0, const float* __restrict__ c0,
    const float* __restrict__ pre_f, const float* __restrict__ pre_b,
    float* __restrict__ hcat, int* __restrict__ flag, float* __restrict__ sink)
{
  __shared__ float hbuf[2][HH];
  if (blockIdx.x >= 2) {
    if (threadIdx.x < 64)
      ballast_spin<512>(flag, 2, (float)(blockIdx.x * 64 + threadIdx.x), sink);
    return;
  }
  const int dir = blockIdx.x;
  const float* __restrict__ Whh = dir ? Whh_b : Whh_f;
  const float* __restrict__ pre = dir ? pre_b : pre_f;
  const int j = threadIdx.x;
  const int g = j & 3;        // 0=i,1=f,2=g,3=o
  const int d = j >> 2;       // hidden dim
  const int r = (g << 7) | d; // Whh row
  float2 w[64];
  {
    const float2* wsrc = (const float2*)(Whh + r * 128);
#pragma unroll
    for (int q = 0; q < 64; ++q) w[q] = wsrc[q];
  }
  float c = c0[dir * HH + d];
  if (g == 0) hbuf[0][d] = h0[dir * HH + d];
  __syncthreads();
  float pcur = pre[(dir ? (T_LEN - 1) : 0) * G4 + j];
  float pn1  = pre[(dir ? (T_LEN - 2) : 1) * G4 + j];

  for (int s = 0; s < T_LEN; ++s) {
    const int t  = dir ? (T_LEN - 1 - s) : s;
    const int s2 = (s + 2 < T_LEN) ? (s + 2) : (T_LEN - 1);
    const int t2 = dir ? (T_LEN - 1 - s2) : s2;
    const float pn2 = pre[t2 * G4 + j];      // depth-2 prefetch

    const float4* h4 = (const float4*)hbuf[s & 1];
    float2 a0 = {0.f, 0.f}, a1 = {0.f, 0.f}, a2 = {0.f, 0.f}, a3 = {0.f, 0.f};
#pragma unroll
    for (int q = 0; q < 32; q += 2) {
      float4 hva = h4[q];
      float4 hvb = h4[q + 1];
      pkfma(a0, w[2*q + 0], make_float2(hva.x, hva.y));
      pkfma(a1, w[2*q + 1], make_float2(hva.z, hva.w));
      pkfma(a2, w[2*q + 2], make_float2(hvb.x, hvb.y));
      pkfma(a3, w[2*q + 3], make_float2(hvb.z, hvb.w));
    }
    const float sum = ((a0.x + a0.y) + (a1.x + a1.y)) +
                      ((a2.x + a2.y) + (a3.x + a3.y));
    const float acc = sum + pcur;
    pcur = pn1; pn1 = pn2;

    const float sc = (g == 2) ? 2.0f : 1.0f;
    const float ev = __expf(-sc * acc);
    const float sg = 1.0f / (1.0f + ev);
    const float act = (g == 2) ? (2.0f * sg - 1.0f) : sg;
    const float iv  = quadbcast<0x00>(act);   // DPP: VALU pipe, no LDS
    const float fv  = quadbcast<0x55>(act);
    const float gv  = quadbcast<0xAA>(act);
    const float ovv = quadbcast<0xFF>(act);
    c = fv * c + iv * gv;
    const float e2 = __expf(-2.0f * c);
    const float th = 2.0f / (1.0f + e2) - 1.0f;
    const float h = ovv * th;
    if (g == 0) {
      hbuf[(s + 1) & 1][d] = h;              // double-buffer: 1 barrier/step
      hcat[t * (2 * HH) + dir * HH + d] = h; // fire-and-forget
    }
    __syncthreads();
  }
  if (j == 0) atomicAdd(flag, 1);            // release ballast
}

// ---------------------------------------------------------------------------
// K3: feats32[t][k] = W_out[k] . hcat[t] + b_out[k]   (stride-32 layout)
// ---------------------------------------------------------------------------
__global__ __launch_bounds__(256) void k_feats(
    const float* __restrict__ hcat, const float* __restrict__ Wout,
    const float* __restrict__ bout, float* __restrict__ feats32)
{
  const int t0 = blockIdx.x * 32;
  __shared__ float hsh[32 * 257];
  __shared__ float wsh[KT * 256];
  __shared__ float bsh[KT];
  const int tid = threadIdx.x;
  for (int i = tid; i < 32 * 256; i += 256) {
    int tl = i >> 8, dd = i & 255;
    hsh[tl * 257 + dd] = hcat[(t0 + tl) * 256 + dd];
  }
  for (int i = tid; i < KT * 256; i += 256) wsh[i] = Wout[i];
  if (tid < KT) bsh[tid] = bout[tid];
  __syncthreads();
  for (int idx = tid; idx < 32 * KT; idx += 256) {
    int tl = idx & 31, k = idx >> 5;
    float a0 = bsh[k], a1 = 0.f, a2 = 0.f, a3 = 0.f;
#pragma unroll 8
    for (int dd = 0; dd < 256; dd += 4) {
      a0 += hsh[tl * 257 + dd + 0] * wsh[k * 256 + dd + 0];
      a1 += hsh[tl * 257 + dd + 1] * wsh[k * 256 + dd + 1];
      a2 += hsh[tl * 257 + dd + 2] * wsh[k * 256 + dd + 2];
      a3 += hsh[tl * 257 + dd + 3] * wsh[k * 256 + dd + 3];
    }
    feats32[(t0 + tl) * 32 + k] = ((a0 + a1) + (a2 + a3));
  }
}

// ---------------------------------------------------------------------------
// K4: sequential Viterbi forward (R6 version — hit chain bound w/ ballast).
// ---------------------------------------------------------------------------
__global__ __launch_bounds__(64) void k_vit_fwd(
    const float* __restrict__ feats32, const float* __restrict__ trans,
    float* __restrict__ fvstore, float* __restrict__ out, int* __restrict__ misc,
    int* __restrict__ flag, float* __restrict__ sink)
{
  if (blockIdx.x >= 1) {
    ballast_spin<256>(flag, 1, (float)(blockIdx.x * 64 + threadIdx.x), sink);
    return;
  }
  const int j = threadIdx.x;
  const int j32 = j & 31;
  float trow[KT];
#pragma unroll
  for (int i = 0; i < KT; ++i)
    trow[i] = (j < KT) ? ((j == START_T || i == STOP_T) ? NEGV : trans[j * KT + i]) : NEGV;
  float fvn = (j == START_T) ? 0.0f : NEGV;
  float pf[8];
#pragma unroll
  for (int q = 0; q < 8; ++q) pf[q] = feats32[q * 32 + j32];

#define MAX3(a,b,cc) fmaxf(fmaxf((a),(b)),(cc))
#define CAND(i) (rl(fvn, (i)) + trow[(i)])

  for (int tb = 0; tb < T_LEN; tb += 8) {
#pragma unroll
    for (int q = 0; q < 8; ++q) {
      const int t = tb + q;
      fvstore[t * 64 + j] = fvn;                  // off-chain, all lanes
      float m0 = MAX3(CAND(0),  CAND(1),  CAND(2));
      float m1 = MAX3(CAND(3),  CAND(4),  CAND(5));
      float m2 = MAX3(CAND(6),  CAND(7),  CAND(8));
      float m3 = MAX3(CAND(9),  CAND(10), CAND(11));
      float m4 = MAX3(CAND(12), CAND(13), CAND(14));
      float m5 = MAX3(CAND(15), CAND(16), CAND(17));
      float m6 = MAX3(CAND(18), CAND(19), CAND(20));
      float m7 = fmaxf(CAND(21), CAND(22));
      float n0 = MAX3(m0, m1, m2);
      float n1 = MAX3(m3, m4, m5);
      float n2 = fmaxf(m6, m7);
      const float best = MAX3(n0, n1, n2);        // exact max: order-free
      fvn = best + pf[q];
      const int tpf = t + 8;
      const int tc = (tpf < T_LEN) ? tpf : (T_LEN - 1);
      pf[q] = feats32[tc * 32 + j32];             // unconditional
    }
  }
  const float trS = (j < KT) ? ((j == STOP_T) ? NEGV : trans[STOP_T * KT + j]) : 0.0f;
  float term = (j < KT) ? (fvn + trS) : -3.0e38f;
  int idx = (j < KT) ? j : 63;
#pragma unroll
  for (int off = 16; off >= 1; off >>= 1) {
    float ovl = __shfl_xor(term, off);
    int oi = __shfl_xor(idx, off);
    if (ovl > term || (ovl == term && oi < idx)) { term = ovl; idx = oi; }
  }
  if (j == 0) { out[0] = term; misc[0] = idx; atomicAdd(flag, 1); }
}

// ---------------------------------------------------------------------------
// K4b: parallel backpointers from stored fv (bitwise-identical candidates,
// strict-> first-max == jnp.argmax).
// ---------------------------------------------------------------------------
__global__ __launch_bounds__(256) void k_bptr(
    const float* __restrict__ fvstore, const float* __restrict__ trans,
    unsigned char* __restrict__ bptr)
{
  const int t0 = blockIdx.x * 32;
  __shared__ float fv[32 * 24];
  __shared__ float trc[KT * KT];
  const int tid = threadIdx.x;
  for (int i = tid; i < 32 * 24; i += 256) {
    int tl = i / 24, e = i - tl * 24;
    fv[i] = fvstore[(t0 + tl) * 64 + e];
  }
  for (int i = tid; i < KT * KT; i += 256) {
    int jj = i / KT, ii = i - jj * KT;
    trc[i] = (jj == START_T || ii == STOP_T) ? NEGV : trans[i];
  }
  __syncthreads();
  for (int p = tid; p < 32 * KT; p += 256) {
    int tl = p / KT, jj = p - tl * KT;
    const float* fvr = fv + tl * 24;
    const float* tr = trc + jj * KT;
    float best = fvr[0] + tr[0]; int bi = 0;
#pragma unroll
    for (int i = 1; i < KT; ++i) {
      float v = fvr[i] + tr[i];
      if (v > best) { best = v; bi = i; }
    }
    bptr[(t0 + tl) * KT + jj] = (unsigned char)bi;
  }
}

// ---------------------------------------------------------------------------
// K5: compose 32-step backpointer maps per chunk (parallel).
// ---------------------------------------------------------------------------
__global__ __launch_bounds__(64) void k_compose(
    const unsigned char* __restrict__ bptr, unsigned char* __restrict__ maps)
{
  const int c = blockIdx.x;
  const int lo = c * 32;
  __shared__ unsigned char rows[32 * 24];
  const int tid = threadIdx.x;
  for (int i = tid; i < 32 * KT; i += 64) {
    int tl = i / KT, e = i - tl * KT;
    rows[tl * 24 + e] = bptr[(lo + tl) * KT + e];
  }
  __syncthreads();
  if (tid < KT) {
    int x = tid;
    for (int tl = 31; tl >= 0; --tl) x = rows[tl * 24 + x];
    maps[c * KT + tid] = (unsigned char)x;
  }
}

// K6: sequential scan over 256 chunk maps.
__global__ __launch_bounds__(64) void k_backscan(
    const unsigned char* __restrict__ maps, const int* __restrict__ misc,
    int* __restrict__ btags)
{
  __shared__ unsigned char msh[256 * KT];
  const int tid = threadIdx.x;
  for (int i = tid; i < 256 * KT; i += 64) msh[i] = maps[i];
  __syncthreads();
  if (tid == 0) {
    int e = misc[0];
    for (int c = 255; c >= 0; --c) { btags[c] = e; e = msh[c * KT + e]; }
  }
}

// K7: evaluate interior path per chunk (parallel), write tags as floats.
__global__ __launch_bounds__(64) void k_backeval(
    const unsigned char* __restrict__ bptr, const int* __restrict__ btags,
    float* __restrict__ out)
{
  const int c = blockIdx.x;
  const int lo = c * 32;
  __shared__ unsigned char rows[32 * 24];
  __shared__ int tags[32];
  const int tid = threadIdx.x;
  for (int i = tid; i < 32 * KT; i += 64) {
    int tl = i / KT, e = i - tl * KT;
    rows[tl * 24 + e] = bptr[(lo + tl) * KT + e];
  }
  __syncthreads();
  if (tid == 0) {
    int tg = btags[c];
    tags[31] = tg;
    for (int tl = 31; tl >= 1; --tl) { tg = rows[tl * 24 + tg]; tags[tl - 1] = tg; }
  }
  __syncthreads();
  if (tid < 32) out[1 + lo + tid] = (float)tags[tid];
}

// ---------------------------------------------------------------------------
extern "C" void kernel_launch(void* const* d_in, const int* in_sizes, int n_in,
                              void* d_out, int out_size, void* d_ws, size_t ws_size,
                              hipStream_t stream) {
  const int*   sentence = (const int*)d_in[0];
  const float* embed    = (const float*)d_in[1];
  const float* Wih_f    = (const float*)d_in[2];
  const float* Whh_f    = (const float*)d_in[3];
  const float* bih_f    = (const float*)d_in[4];
  const float* bhh_f    = (const float*)d_in[5];
  const float* Wih_b    = (const float*)d_in[6];
  const float* Whh_b    = (const float*)d_in[7];
  const float* bih_b    = (const float*)d_in[8];
  const float* bhh_b    = (const float*)d_in[9];
  const float* Wout     = (const float*)d_in[10];
  const float* bout     = (const float*)d_in[11];
  const float* trans    = (const float*)d_in[12];
  const float* h0       = (const float*)d_in[13];
  const float* c0       = (const float*)d_in[14];
  float* out = (float*)d_out;

  float* ws = (float*)d_ws;
  float* pre_f = ws;                               // [T][512]
  float* pre_b = pre_f + (size_t)T_LEN * G4;       // [T][512]
  float* hcat  = pre_b + (size_t)T_LEN * G4;       // [T][256]
  float* feats32 = hcat + (size_t)T_LEN * 2 * HH;  // [T][32]
  unsigned char* bptr = (unsigned char*)(feats32 + (size_t)T_LEN * 32);
  unsigned char* maps = bptr + (size_t)T_LEN * KT;
  int* btags = (int*)(maps + 256 * KT);
  int* misc  = btags + 256;
  int* flags = misc + 8;                           // [0]=lstm done, [1]=vit done
  float* sink = (float*)(flags + 8);
  float* fvstore = pre_f;                          // [T][64], pre dead after k_lstm

  hipMemsetAsync(flags, 0, 8 * sizeof(int), stream);
  k_pre<<<512, 512, 0, stream>>>(sentence, embed, Wih_f, bih_f, bhh_f,
                                 Wih_b, bih_b, bhh_b, pre_f, pre_b);
  k_lstm<<<256, 512, 0, stream>>>(Whh_f, Whh_b, h0, c0, pre_f, pre_b, hcat,
                                  flags + 0, sink);
  k_feats<<<256, 256, 0, stream>>>(hcat, Wout, bout, feats32);
  k_vit_fwd<<<256, 64, 0, stream>>>(feats32, trans, fvstore, out, misc,
                                    flags + 1, sink);
  k_bptr<<<256, 256, 0, stream>>>(fvstore, trans, bptr);
  k_compose<<<256, 64, 0, stream>>>(bptr, maps);
  k_backscan<<<1, 64, 0, stream>>>(maps, misc, btags);
  k_backeval<<<256, 64, 0, stream>>>(bptr, btags, out);
}

// Round 2
// 7406.312 us; speedup vs baseline: 1.2068x; 1.2055x over previous
//
#include <hip/hip_runtime.h>

#define T_LEN 8192
#define HH 128
#define G4 512
#define E_DIM 50
#define KT 23
#define START_T 21
#define STOP_T 22
#define NEGV -10000.0f

__device__ __forceinline__ float rl(float v, int lane) {
  return __int_as_float(__builtin_amdgcn_readlane(__float_as_int(v), lane));
}

template <int CTRL>
__device__ __forceinline__ float quadbcast(float x) {
  return __int_as_float(
      __builtin_amdgcn_mov_dpp(__float_as_int(x), CTRL, 0xF, 0xF, true));
}

// quad_perm rotate: lane l takes value from lane (l-1)&3.  sel=[3,0,1,2] -> 0x93
__device__ __forceinline__ float quadrot(float x) {
  return __int_as_float(
      __builtin_amdgcn_mov_dpp(__float_as_int(x), 0x93, 0xF, 0xF, true));
}

// Packed fp32 FMA (VOP3P, arch-VGPR forced).
__device__ __forceinline__ void pkfma(float2& acc, const float2 w, const float2 h) {
  asm volatile("v_pk_fma_f32 %0, %1, %2, %0" : "+v"(acc) : "v"(w), "v"(h));
}

// LIGHT ballast: ONE dependent-chain FMA wave per CU (~1.6% VALU duty).
template <int BURST>
__device__ __forceinline__ void ballast_spin(const int* flag, int target, float seed,
                                             float* sink) {
  float x = seed;
  const float aa = 1.0000001f, bb = 1e-7f;
  while (__hip_atomic_load(flag, __ATOMIC_RELAXED, __HIP_MEMORY_SCOPE_AGENT) < target) {
#pragma unroll
    for (int q = 0; q < BURST; ++q) x = fmaf(x, aa, bb);
  }
  if (x == 12345.678f) *sink = x;   // unprovable -> loop not removable
}

// ---------------------------------------------------------------------------
// K1: pre[t][j] = Wih[row(j)] . x_t + bih + bhh   (row permuted: r=((j&3)<<7)|(j>>2))
// ---------------------------------------------------------------------------
__global__ __launch_bounds__(512) void k_pre(
    const int* __restrict__ sentence, const float* __restrict__ embed,
    const float* __restrict__ Wih_f, const float* __restrict__ bih_f, const float* __restrict__ bhh_f,
    const float* __restrict__ Wih_b, const float* __restrict__ bih_b, const float* __restrict__ bhh_b,
    float* __restrict__ pre_f, float* __restrict__ pre_b)
{
  const int dir = blockIdx.x >> 8;
  const int t0 = (blockIdx.x & 255) * 32;
  const float* __restrict__ Wih = dir ? Wih_b : Wih_f;
  const float* __restrict__ bi  = dir ? bih_b : bih_f;
  const float* __restrict__ bh  = dir ? bhh_b : bhh_f;
  float* __restrict__ pre = dir ? pre_b : pre_f;
  const int j = threadIdx.x;
  const int r = ((j & 3) << 7) | (j >> 2);
  float w[E_DIM];
  {
    const float2* w2 = (const float2*)(Wih + r * E_DIM);
#pragma unroll
    for (int q = 0; q < 25; ++q) { float2 v = w2[q]; w[2*q] = v.x; w[2*q+1] = v.y; }
  }
  const float bias = bi[r] + bh[r];
  __shared__ float xs[32][E_DIM];
  __shared__ int sidx[32];
  if (j < 32) sidx[j] = sentence[t0 + j];
  __syncthreads();
  for (int i = j; i < 32 * E_DIM; i += 512) {
    int tl = i / E_DIM;
    int e = i - tl * E_DIM;
    xs[tl][e] = embed[sidx[tl] * E_DIM + e];
  }
  __syncthreads();
  for (int tl = 0; tl < 32; ++tl) {
    float a0 = bias, a1 = 0.f;
#pragma unroll
    for (int e = 0; e < E_DIM; e += 2) {
      a0 += w[e]     * xs[tl][e];
      a1 += w[e + 1] * xs[tl][e + 1];
    }
    pre[(t0 + tl) * G4 + j] = a0 + a1;
  }
}

// ---------------------------------------------------------------------------
// K2: serial LSTM, 1 CU/dir.
//
// R2 REDESIGN (data-redelivery bound at 2280 cy/step):
//  * Slice decomposition: quad Q owns hidden dim d=Q's 4 gate-rows. Lane l of
//    the quad reads ONLY h-slice l (interleaved float4 chunks c=l+4q, q=0..7:
//    4 distinct addrs span 16 banks -> conflict-free, and LDS return traffic
//    drops 4x: 256KB -> 64KB/step/CU).
//  * Each lane accumulates partials for ALL 4 gate-rows over its slice
//    (reg_m = P[(l-m)&3][l]); a 3-step DPP quad-rotation reduce (0x93) leaves
//    lane l with the FULL dot for gate gstar=(l+1)&3.
//  * Weights (128 floats/thread, irreducible at 512 threads) are pinned into
//    arch VGPRs with no-op asm "+v" defs so the allocator CANNOT remat the
//    loop-invariant Whh loads into the 8192-step loop (R1: VGPR_Count=80
//    proved it was doing exactly that -> 256KB/step L2 re-reads).
// ---------------------------------------------------------------------------
__global__ __launch_bounds__(512, 1) void k_lstm(
    const float* __restrict__ Whh_f, const float* __restrict__ Whh_b,
    const float* __restrict__ h0, const float* __restrict__ c0,
    const float* __restrict__ pre_f, const float* __restrict__ pre_b,
    float* __restrict__ hcat, int* __restrict__ flag, float* __restrict__ sink)
{
  __shared__ float hbuf[2][HH];
  if (blockIdx.x >= 2) {
    if (threadIdx.x < 64)
      ballast_spin<512>(flag, 2, (float)(blockIdx.x * 64 + threadIdx.x), sink);
    return;
  }
  const int dir = blockIdx.x;
  const float* __restrict__ Whh = dir ? Whh_b : Whh_f;
  const float* __restrict__ pre = dir ? pre_b : pre_f;
  const int j = threadIdx.x;
  const int l = j & 3;               // slice / lane-in-quad
  const int Q = j >> 2;              // hidden dim owned by this quad
  const int gstar = (l + 1) & 3;     // gate this lane holds after the reduce
  const int jstar = (Q << 2) | gstar;  // pre[] column for gate gstar @ dim Q

  // w[m*16 + 2q + h]: float2 of Whh[row((l-m)&3, Q)], chunk c=l+4q, half h.
  float2 w[64];
#pragma unroll
  for (int m = 0; m < 4; ++m) {
    const int g = (l - m) & 3;
    const float4* src = (const float4*)(Whh + (((g << 7) | Q) << 7));
#pragma unroll
    for (int q = 0; q < 8; ++q) {
      float4 v = src[l + 4 * q];
      w[m * 16 + 2 * q]     = make_float2(v.x, v.y);
      w[m * 16 + 2 * q + 1] = make_float2(v.z, v.w);
    }
  }
  // Pin: opaque defs -> loads above cannot be rematerialized into the loop.
#define PIN8(B) asm volatile("" : "+v"(w[B]), "+v"(w[B+1]), "+v"(w[B+2]), \
    "+v"(w[B+3]), "+v"(w[B+4]), "+v"(w[B+5]), "+v"(w[B+6]), "+v"(w[B+7]))
  PIN8(0); PIN8(8); PIN8(16); PIN8(24); PIN8(32); PIN8(40); PIN8(48); PIN8(56);
#undef PIN8

  float c = c0[dir * HH + Q];
  if (l == 0) hbuf[0][Q] = h0[dir * HH + Q];
  __syncthreads();
  float pcur = pre[(dir ? (T_LEN - 1) : 0) * G4 + jstar];
  float pn1  = pre[(dir ? (T_LEN - 2) : 1) * G4 + jstar];

  for (int s = 0; s < T_LEN; ++s) {
    const int t  = dir ? (T_LEN - 1 - s) : s;
    const int s2 = (s + 2 < T_LEN) ? (s + 2) : (T_LEN - 1);
    const int t2 = dir ? (T_LEN - 1 - s2) : s2;
    const float pn2 = pre[t2 * G4 + jstar];  // depth-2 prefetch

    const float4* h4 = (const float4*)hbuf[s & 1];
    float2 a0 = {0.f, 0.f}, a1 = {0.f, 0.f}, a2 = {0.f, 0.f}, a3 = {0.f, 0.f};
#pragma unroll
    for (int q = 0; q < 8; ++q) {
      float4 hv = h4[l + 4 * q];             // slice l, chunk l+4q
      const float2 hlo = make_float2(hv.x, hv.y);
      const float2 hhi = make_float2(hv.z, hv.w);
      pkfma(a0, w[      2 * q], hlo); pkfma(a0, w[      2 * q + 1], hhi);
      pkfma(a1, w[16 + 2 * q], hlo); pkfma(a1, w[16 + 2 * q + 1], hhi);
      pkfma(a2, w[32 + 2 * q], hlo); pkfma(a2, w[32 + 2 * q + 1], hhi);
      pkfma(a3, w[48 + 2 * q], hlo); pkfma(a3, w[48 + 2 * q + 1], hhi);
    }
    // horizontal halves, then 3-step quad rotation reduce-scatter:
    // lane l ends with full dot for gate gstar=(l+1)&3.
    const float p0 = a0.x + a0.y;
    const float p1 = a1.x + a1.y;
    const float p2 = a2.x + a2.y;
    const float p3 = a3.x + a3.y;
    float red = p0;
    red = quadrot(red) + p1;
    red = quadrot(red) + p2;
    red = quadrot(red) + p3;
    const float acc = red + pcur;
    pcur = pn1; pn1 = pn2;

    const float sc = (gstar == 2) ? 2.0f : 1.0f;
    const float ev = __expf(-sc * acc);
    const float sg = 1.0f / (1.0f + ev);
    const float act = (gstar == 2) ? (2.0f * sg - 1.0f) : sg;
    // gate g sits at lane (g+3)&3 of the quad
    const float iv  = quadbcast<0xFF>(act);  // gate 0 <- lane 3
    const float fv  = quadbcast<0x00>(act);  // gate 1 <- lane 0
    const float gv  = quadbcast<0x55>(act);  // gate 2 <- lane 1
    const float ovv = quadbcast<0xAA>(act);  // gate 3 <- lane 2
    c = fv * c + iv * gv;
    const float e2 = __expf(-2.0f * c);
    const float th = 2.0f / (1.0f + e2) - 1.0f;
    const float h = ovv * th;
    if (l == 0) {
      hbuf[(s + 1) & 1][Q] = h;              // double-buffer: 1 barrier/step
      hcat[t * (2 * HH) + dir * HH + Q] = h; // fire-and-forget
    }
    __syncthreads();
  }
  if (j == 0) atomicAdd(flag, 1);            // release ballast
}

// ---------------------------------------------------------------------------
// K3: feats32[t][k] = W_out[k] . hcat[t] + b_out[k]   (stride-32 layout)
// ---------------------------------------------------------------------------
__global__ __launch_bounds__(256) void k_feats(
    const float* __restrict__ hcat, const float* __restrict__ Wout,
    const float* __restrict__ bout, float* __restrict__ feats32)
{
  const int t0 = blockIdx.x * 32;
  __shared__ float hsh[32 * 257];
  __shared__ float wsh[KT * 256];
  __shared__ float bsh[KT];
  const int tid = threadIdx.x;
  for (int i = tid; i < 32 * 256; i += 256) {
    int tl = i >> 8, dd = i & 255;
    hsh[tl * 257 + dd] = hcat[(t0 + tl) * 256 + dd];
  }
  for (int i = tid; i < KT * 256; i += 256) wsh[i] = Wout[i];
  if (tid < KT) bsh[tid] = bout[tid];
  __syncthreads();
  for (int idx = tid; idx < 32 * KT; idx += 256) {
    int tl = idx & 31, k = idx >> 5;
    float a0 = bsh[k], a1 = 0.f, a2 = 0.f, a3 = 0.f;
#pragma unroll 8
    for (int dd = 0; dd < 256; dd += 4) {
      a0 += hsh[tl * 257 + dd + 0] * wsh[k * 256 + dd + 0];
      a1 += hsh[tl * 257 + dd + 1] * wsh[k * 256 + dd + 1];
      a2 += hsh[tl * 257 + dd + 2] * wsh[k * 256 + dd + 2];
      a3 += hsh[tl * 257 + dd + 3] * wsh[k * 256 + dd + 3];
    }
    feats32[(t0 + tl) * 32 + k] = ((a0 + a1) + (a2 + a3));
  }
}

// ---------------------------------------------------------------------------
// K4: sequential Viterbi forward (R6 version — hit chain bound w/ ballast).
// ---------------------------------------------------------------------------
__global__ __launch_bounds__(64) void k_vit_fwd(
    const float* __restrict__ feats32, const float* __restrict__ trans,
    float* __restrict__ fvstore, float* __restrict__ out, int* __restrict__ misc,
    int* __restrict__ flag, float* __restrict__ sink)
{
  if (blockIdx.x >= 1) {
    ballast_spin<256>(flag, 1, (float)(blockIdx.x * 64 + threadIdx.x), sink);
    return;
  }
  const int j = threadIdx.x;
  const int j32 = j & 31;
  float trow[KT];
#pragma unroll
  for (int i = 0; i < KT; ++i)
    trow[i] = (j < KT) ? ((j == START_T || i == STOP_T) ? NEGV : trans[j * KT + i]) : NEGV;
  float fvn = (j == START_T) ? 0.0f : NEGV;
  float pf[8];
#pragma unroll
  for (int q = 0; q < 8; ++q) pf[q] = feats32[q * 32 + j32];

#define MAX3(a,b,cc) fmaxf(fmaxf((a),(b)),(cc))
#define CAND(i) (rl(fvn, (i)) + trow[(i)])

  for (int tb = 0; tb < T_LEN; tb += 8) {
#pragma unroll
    for (int q = 0; q < 8; ++q) {
      const int t = tb + q;
      fvstore[t * 64 + j] = fvn;                  // off-chain, all lanes
      float m0 = MAX3(CAND(0),  CAND(1),  CAND(2));
      float m1 = MAX3(CAND(3),  CAND(4),  CAND(5));
      float m2 = MAX3(CAND(6),  CAND(7),  CAND(8));
      float m3 = MAX3(CAND(9),  CAND(10), CAND(11));
      float m4 = MAX3(CAND(12), CAND(13), CAND(14));
      float m5 = MAX3(CAND(15), CAND(16), CAND(17));
      float m6 = MAX3(CAND(18), CAND(19), CAND(20));
      float m7 = fmaxf(CAND(21), CAND(22));
      float n0 = MAX3(m0, m1, m2);
      float n1 = MAX3(m3, m4, m5);
      float n2 = fmaxf(m6, m7);
      const float best = MAX3(n0, n1, n2);        // exact max: order-free
      fvn = best + pf[q];
      const int tpf = t + 8;
      const int tc = (tpf < T_LEN) ? tpf : (T_LEN - 1);
      pf[q] = feats32[tc * 32 + j32];             // unconditional
    }
  }
  const float trS = (j < KT) ? ((j == STOP_T) ? NEGV : trans[STOP_T * KT + j]) : 0.0f;
  float term = (j < KT) ? (fvn + trS) : -3.0e38f;
  int idx = (j < KT) ? j : 63;
#pragma unroll
  for (int off = 16; off >= 1; off >>= 1) {
    float ovl = __shfl_xor(term, off);
    int oi = __shfl_xor(idx, off);
    if (ovl > term || (ovl == term && oi < idx)) { term = ovl; idx = oi; }
  }
  if (j == 0) { out[0] = term; misc[0] = idx; atomicAdd(flag, 1); }
}

// ---------------------------------------------------------------------------
// K4b: parallel backpointers from stored fv (bitwise-identical candidates,
// strict-> first-max == jnp.argmax).
// ---------------------------------------------------------------------------
__global__ __launch_bounds__(256) void k_bptr(
    const float* __restrict__ fvstore, const float* __restrict__ trans,
    unsigned char* __restrict__ bptr)
{
  const int t0 = blockIdx.x * 32;
  __shared__ float fv[32 * 24];
  __shared__ float trc[KT * KT];
  const int tid = threadIdx.x;
  for (int i = tid; i < 32 * 24; i += 256) {
    int tl = i / 24, e = i - tl * 24;
    fv[i] = fvstore[(t0 + tl) * 64 + e];
  }
  for (int i = tid; i < KT * KT; i += 256) {
    int jj = i / KT, ii = i - jj * KT;
    trc[i] = (jj == START_T || ii == STOP_T) ? NEGV : trans[i];
  }
  __syncthreads();
  for (int p = tid; p < 32 * KT; p += 256) {
    int tl = p / KT, jj = p - tl * KT;
    const float* fvr = fv + tl * 24;
    const float* tr = trc + jj * KT;
    float best = fvr[0] + tr[0]; int bi = 0;
#pragma unroll
    for (int i = 1; i < KT; ++i) {
      float v = fvr[i] + tr[i];
      if (v > best) { best = v; bi = i; }
    }
    bptr[(t0 + tl) * KT + jj] = (unsigned char)bi;
  }
}

// ---------------------------------------------------------------------------
// K5: compose 32-step backpointer maps per chunk (parallel).
// ---------------------------------------------------------------------------
__global__ __launch_bounds__(64) void k_compose(
    const unsigned char* __restrict__ bptr, unsigned char* __restrict__ maps)
{
  const int c = blockIdx.x;
  const int lo = c * 32;
  __shared__ unsigned char rows[32 * 24];
  const int tid = threadIdx.x;
  for (int i = tid; i < 32 * KT; i += 64) {
    int tl = i / KT, e = i - tl * KT;
    rows[tl * 24 + e] = bptr[(lo + tl) * KT + e];
  }
  __syncthreads();
  if (tid < KT) {
    int x = tid;
    for (int tl = 31; tl >= 0; --tl) x = rows[tl * 24 + x];
    maps[c * KT + tid] = (unsigned char)x;
  }
}

// K6: sequential scan over 256 chunk maps.
__global__ __launch_bounds__(64) void k_backscan(
    const unsigned char* __restrict__ maps, const int* __restrict__ misc,
    int* __restrict__ btags)
{
  __shared__ unsigned char msh[256 * KT];
  const int tid = threadIdx.x;
  for (int i = tid; i < 256 * KT; i += 64) msh[i] = maps[i];
  __syncthreads();
  if (tid == 0) {
    int e = misc[0];
    for (int c = 255; c >= 0; --c) { btags[c] = e; e = msh[c * KT + e]; }
  }
}

// K7: evaluate interior path per chunk (parallel), write tags as floats.
__global__ __launch_bounds__(64) void k_backeval(
    const unsigned char* __restrict__ bptr, const int* __restrict__ btags,
    float* __restrict__ out)
{
  const int c = blockIdx.x;
  const int lo = c * 32;
  __shared__ unsigned char rows[32 * 24];
  __shared__ int tags[32];
  const int tid = threadIdx.x;
  for (int i = tid; i < 32 * KT; i += 64) {
    int tl = i / KT, e = i - tl * KT;
    rows[tl * 24 + e] = bptr[(lo + tl) * KT + e];
  }
  __syncthreads();
  if (tid == 0) {
    int tg = btags[c];
    tags[31] = tg;
    for (int tl = 31; tl >= 1; --tl) { tg = rows[tl * 24 + tg]; tags[tl - 1] = tg; }
  }
  __syncthreads();
  if (tid < 32) out[1 + lo + tid] = (float)tags[tid];
}

// ---------------------------------------------------------------------------
extern "C" void kernel_launch(void* const* d_in, const int* in_sizes, int n_in,
                              void* d_out, int out_size, void* d_ws, size_t ws_size,
                              hipStream_t stream) {
  const int*   sentence = (const int*)d_in[0];
  const float* embed    = (const float*)d_in[1];
  const float* Wih_f    = (const float*)d_in[2];
  const float* Whh_f    = (const float*)d_in[3];
  const float* bih_f    = (const float*)d_in[4];
  const float* bhh_f    = (const float*)d_in[5];
  const float* Wih_b    = (const float*)d_in[6];
  const float* Whh_b    = (const float*)d_in[7];
  const float* bih_b    = (const float*)d_in[8];
  const float* bhh_b    = (const float*)d_in[9];
  const float* Wout     = (const float*)d_in[10];
  const float* bout     = (const float*)d_in[11];
  const float* trans    = (const float*)d_in[12];
  const float* h0       = (const float*)d_in[13];
  const float* c0       = (const float*)d_in[14];
  float* out = (float*)d_out;

  float* ws = (float*)d_ws;
  float* pre_f = ws;                               // [T][512]
  float* pre_b = pre_f + (size_t)T_LEN * G4;       // [T][512]
  float* hcat  = pre_b + (size_t)T_LEN * G4;       // [T][256]
  float* feats32 = hcat + (size_t)T_LEN * 2 * HH;  // [T][32]
  unsigned char* bptr = (unsigned char*)(feats32 + (size_t)T_LEN * 32);
  unsigned char* maps = bptr + (size_t)T_LEN * KT;
  int* btags = (int*)(maps + 256 * KT);
  int* misc  = btags + 256;
  int* flags = misc + 8;                           // [0]=lstm done, [1]=vit done
  float* sink = (float*)(flags + 8);
  float* fvstore = pre_f;                          // [T][64], pre dead after k_lstm

  hipMemsetAsync(flags, 0, 8 * sizeof(int), stream);
  k_pre<<<512, 512, 0, stream>>>(sentence, embed, Wih_f, bih_f, bhh_f,
                                 Wih_b, bih_b, bhh_b, pre_f, pre_b);
  k_lstm<<<256, 512, 0, stream>>>(Whh_f, Whh_b, h0, c0, pre_f, pre_b, hcat,
                                  flags + 0, sink);
  k_feats<<<256, 256, 0, stream>>>(hcat, Wout, bout, feats32);
  k_vit_fwd<<<256, 64, 0, stream>>>(feats32, trans, fvstore, out, misc,
                                    flags + 1, sink);
  k_bptr<<<256, 256, 0, stream>>>(fvstore, trans, bptr);
  k_compose<<<256, 64, 0, stream>>>(bptr, maps);
  k_backscan<<<1, 64, 0, stream>>>(maps, misc, btags);
  k_backeval<<<256, 64, 0, stream>>>(bptr, btags, out);
}